// Round 15
// baseline (158.749 us; speedup 1.0000x reference)
//
#include <hip/hip_runtime.h>

#define NROWS 131072
#define DIM 64
#define KCODES 1024
#define MARGIN_DOT 2.5e-4f
#define WIN_FILTER 5e-4f
#define FLAG_CAP 16384
#define OUT_BLOCKS 2048
#define REFINE_BLOCKS 2048

typedef short bf16x8 __attribute__((ext_vector_type(8)));
typedef float f32x4 __attribute__((ext_vector_type(4)));

__device__ __forceinline__ unsigned short f32_to_bf16_rne(float f) {
  unsigned u = __float_as_uint(f);
  u += 0x7FFFu + ((u >> 16) & 1u);
  return (unsigned short)(u >> 16);
}

// async global->LDS, 16B per lane; lds dest = wave-uniform base + lane*16
__device__ __forceinline__ void gload_lds16(const void* g, void* l) {
  __builtin_amdgcn_global_load_lds(
      (const __attribute__((address_space(1))) unsigned int*)g,
      (__attribute__((address_space(3))) unsigned int*)l, 16, 0, 0);
}

// load 8 f32, split into bf16 hi/lo planes (RNE both)
__device__ __forceinline__ void cvt_split8(const float* p, bf16x8* hi, bf16x8* lo) {
  float4 f0 = *(const float4*)p;
  float4 f1 = *(const float4*)(p + 4);
  float fv[8] = {f0.x, f0.y, f0.z, f0.w, f1.x, f1.y, f1.z, f1.w};
  union { bf16x8 v; unsigned short u[8]; } H, L;
#pragma unroll
  for (int i = 0; i < 8; i++) {
    unsigned short h = f32_to_bf16_rne(fv[i]);
    float hf = __uint_as_float((unsigned)h << 16);
    H.u[i] = h;
    L.u[i] = f32_to_bf16_rne(fv[i] - hf);
  }
  *hi = H.v;
  *lo = L.v;
}

// ---------------- prep: counters init + enorm64 + swizzled split-bf16 emb tiles ----------------
__global__ __launch_bounds__(64) void vq_prep(const float* __restrict__ emb,
                                              double* __restrict__ enorm64,
                                              unsigned short* __restrict__ ehl,
                                              int* __restrict__ flag_count,
                                              int* __restrict__ done_count) {
  int k = blockIdx.x;
  int d = threadIdx.x;
  if (k == 0 && d == 0) { *flag_count = 0; *done_count = 0; }
  float v = emb[k * 64 + d];
  unsigned short h = f32_to_bf16_rne(v);
  float hf = __uint_as_float((unsigned)h << 16);
  unsigned short l = f32_to_bf16_rne(v - hf);
  int tile = k >> 4, cin = k & 15;
  int sidx = (cin * 64 + d) ^ ((cin & 7) << 3);
  ehl[tile * 2048 + sidx] = h;
  ehl[tile * 2048 + 1024 + sidx] = l;
  double s = (double)v * (double)v;
  for (int off = 32; off > 0; off >>= 1) s += __shfl_down(s, off, 64);
  if (d == 0) enorm64[k] = s;
}

// ---------------- pass B (R13-proven): MFMA argmax-dot, exact unpacked top-2 ----------------
// 1024 blocks x 4 waves; wave owns 32 rows x all codes; 4-slot ring, vmcnt(2).
__global__ __launch_bounds__(256, 4) void vq_passB(
    const float* __restrict__ z, const unsigned short* __restrict__ ehl,
    float* __restrict__ idx_f, int* __restrict__ flag_count,
    int* __restrict__ flag_rows) {
  __shared__ unsigned short lds[4][2048];  // 4 x 4KB tile slots
  const int lane = threadIdx.x & 63;
  const int wv = threadIdx.x >> 6;
  const int lo4 = lane & 15;
  const int hi4 = lane >> 4;
  const int rowb = blockIdx.x * 128 + wv * 32;

  // prologue: stage tiles 0,1 (wave wv copies its 1KB quarter of each)
  gload_lds16(ehl + wv * 512 + lane * 8, &lds[0][wv * 512]);
  gload_lds16(ehl + 2048 + wv * 512 + lane * 8, &lds[1][wv * 512]);

  // z fragments: rt0 row = rowb + lo4, rt1 row = rowb + 16 + lo4
  bf16x8 zh0a, zh1a, zl0a, zl1a, zh0b, zh1b, zl0b, zl1b;
  {
    const float* zr0 = z + (size_t)(rowb + lo4) * 64 + hi4 * 8;
    const float* zr1 = z + (size_t)(rowb + 16 + lo4) * 64 + hi4 * 8;
    cvt_split8(zr0, &zh0a, &zl0a);
    cvt_split8(zr0 + 32, &zh1a, &zl1a);
    cvt_split8(zr1, &zh0b, &zl0b);
    cvt_split8(zr1 + 32, &zh1b, &zl1b);
  }

  float m1a = -3.4e38f, m2a = -3.4e38f, m1b = -3.4e38f, m2b = -3.4e38f;
  int i1a = 0, i1b = 0;
  const int swz = (lo4 & 7) << 3;
  const int i0 = (lo4 * 64 + hi4 * 8) ^ swz;
  const int i1 = (lo4 * 64 + 32 + hi4 * 8) ^ swz;

  for (int ct = 0; ct < 64; ct++) {
    int tn = (ct + 2 < 64) ? ct + 2 : 63;
    gload_lds16(ehl + tn * 2048 + wv * 512 + lane * 8, &lds[(ct + 2) & 3][wv * 512]);
    asm volatile("s_waitcnt vmcnt(2)" ::: "memory");  // own tile done; 2 in flight
    __builtin_amdgcn_s_barrier();
    asm volatile("" ::: "memory");

    const unsigned short* buf = lds[ct & 3];
    bf16x8 ah0 = *(const bf16x8*)(buf + i0);
    bf16x8 ah1 = *(const bf16x8*)(buf + i1);
    bf16x8 al0 = *(const bf16x8*)(buf + 1024 + i0);
    bf16x8 al1 = *(const bf16x8*)(buf + 1024 + i1);
    const int cbase = ct * 16 + hi4 * 4;

    f32x4 accA = {0.f, 0.f, 0.f, 0.f};
    f32x4 accB = {0.f, 0.f, 0.f, 0.f};
    __builtin_amdgcn_s_setprio(1);
    accA = __builtin_amdgcn_mfma_f32_16x16x32_bf16(ah0, zh0a, accA, 0, 0, 0);
    accB = __builtin_amdgcn_mfma_f32_16x16x32_bf16(ah0, zh0b, accB, 0, 0, 0);
    accA = __builtin_amdgcn_mfma_f32_16x16x32_bf16(ah1, zh1a, accA, 0, 0, 0);
    accB = __builtin_amdgcn_mfma_f32_16x16x32_bf16(ah1, zh1b, accB, 0, 0, 0);
    accA = __builtin_amdgcn_mfma_f32_16x16x32_bf16(al0, zh0a, accA, 0, 0, 0);
    accB = __builtin_amdgcn_mfma_f32_16x16x32_bf16(al0, zh0b, accB, 0, 0, 0);
    accA = __builtin_amdgcn_mfma_f32_16x16x32_bf16(al1, zh1a, accA, 0, 0, 0);
    accB = __builtin_amdgcn_mfma_f32_16x16x32_bf16(al1, zh1b, accB, 0, 0, 0);
    accA = __builtin_amdgcn_mfma_f32_16x16x32_bf16(ah0, zl0a, accA, 0, 0, 0);
    accB = __builtin_amdgcn_mfma_f32_16x16x32_bf16(ah0, zl0b, accB, 0, 0, 0);
    accA = __builtin_amdgcn_mfma_f32_16x16x32_bf16(ah1, zl1a, accA, 0, 0, 0);
    accB = __builtin_amdgcn_mfma_f32_16x16x32_bf16(ah1, zl1b, accB, 0, 0, 0);
    __builtin_amdgcn_s_setprio(0);

    // exact unpacked top-2 + argmax (strict > keeps lowest code per lane)
#pragma unroll
    for (int r = 0; r < 4; r++) {
      int code = cbase + r;
      {
        float s = accA[r];
        float pm = fminf(m1a, s);
        m2a = fmaxf(m2a, pm);
        if (s > m1a) i1a = code;
        m1a = fmaxf(m1a, s);
      }
      {
        float s = accB[r];
        float pm = fminf(m1b, s);
        m2b = fmaxf(m2b, pm);
        if (s > m1b) i1b = code;
        m1b = fmaxf(m1b, s);
      }
    }
  }

  // per-row merge over the 4 lane-groups (xor 16, 32) + emit
#pragma unroll
  for (int rt = 0; rt < 2; rt++) {
    float a1 = rt ? m1b : m1a;
    float a2 = rt ? m2b : m2a;
    int ai = rt ? i1b : i1a;
#pragma unroll
    for (int off = 16; off <= 32; off <<= 1) {
      float b1 = __shfl_xor(a1, off, 64);
      float b2 = __shfl_xor(a2, off, 64);
      int bi = __shfl_xor(ai, off, 64);
      float pm = fminf(a1, b1);
      a2 = fmaxf(fmaxf(a2, b2), pm);
      bool take = (b1 > a1) || (b1 == a1 && bi < ai);
      a1 = fmaxf(a1, b1);
      ai = take ? bi : ai;
    }
    if (lane < 16) {
      int row = rowb + rt * 16 + lane;
      idx_f[row] = (float)ai;
      if (a1 - a2 < MARGIN_DOT) {
        int pos = atomicAdd(flag_count, 1);
        if (pos < FLAG_CAP) flag_rows[pos] = row;
      }
    }
  }
}

// ---------------- refine: R5-proven per-row f32 filter + f64 candidate eval ----------------
__global__ __launch_bounds__(256) void vq_refine(const float* __restrict__ z,
                                                 const float* __restrict__ emb,
                                                 const double* __restrict__ enorm64,
                                                 const int* __restrict__ flag_count,
                                                 const int* __restrict__ flag_rows,
                                                 float* __restrict__ idx_f) {
  __shared__ float zs[64];
  __shared__ float smin[256];
  __shared__ int cand[256];
  __shared__ int ccount;
  __shared__ float A32s;
  int cnt = *flag_count;
  if (cnt > FLAG_CAP) cnt = FLAG_CAP;
  const int t = threadIdx.x;
  for (int i = blockIdx.x; i < cnt; i += gridDim.x) {
    int row = flag_rows[i];
    if (t < 64) zs[t] = z[(size_t)row * 64 + t];
    if (t == 0) ccount = 0;
    __syncthreads();
    if (t == 0) {  // sequential f64 row norm -> f32 (proven path)
      double a = 0.0;
      for (int d = 0; d < 64; d++) { double v = (double)zs[d]; a = fma(v, v, a); }
      A32s = (float)a;
    }
    float s_loc[4];
    float my = 3.4e38f;
#pragma unroll
    for (int q = 0; q < 4; q++) {
      int k = t * 4 + q;
      const float4* er = (const float4*)(emb + (size_t)k * 64);
      float dotf = 0.f;
#pragma unroll
      for (int d4 = 0; d4 < 16; d4++) {
        float4 e4 = er[d4];
        float4 zv = ((const float4*)zs)[d4];
        dotf = fmaf(e4.x, zv.x, dotf);
        dotf = fmaf(e4.y, zv.y, dotf);
        dotf = fmaf(e4.z, zv.z, dotf);
        dotf = fmaf(e4.w, zv.w, dotf);
      }
      s_loc[q] = -dotf;
      my = fminf(my, -dotf);
    }
    smin[t] = my;
    __syncthreads();
    for (int s = 128; s > 0; s >>= 1) {
      if (t < s) smin[t] = fminf(smin[t], smin[t + s]);
      __syncthreads();
    }
    float m1 = smin[0];
#pragma unroll
    for (int q = 0; q < 4; q++) {
      if (s_loc[q] - m1 < WIN_FILTER) {
        int p = atomicAdd(&ccount, 1);
        if (p < 256) cand[p] = t * 4 + q;
      }
    }
    __syncthreads();
    int cc = ccount;
    if (cc > 256) cc = 256;
    if (t < 64) {
      float bm = 3.4e38f;
      int bi = 0x7FFFFFFF;
      for (int c = 0; c < cc; c++) {
        int k = cand[c];
        double p = (double)emb[(size_t)k * 64 + t] * (double)zs[t];
        for (int off = 32; off > 0; off >>= 1) p += __shfl_down(p, off, 64);
        if (t == 0) {
          float C = (float)(2.0 * p);
          float B = (float)enorm64[k];
          float T = A32s + B;
          float dist = T - C;
          if (dist < bm || (dist == bm && k < bi)) { bm = dist; bi = k; }
        }
      }
      if (t == 0) idx_f[row] = (float)bi;
    }
    __syncthreads();
  }
}

// ---------------- outputs: quantized_ste + loss partials + fused final reduce ----------------
// Last-completing block (device-scope counter + threadfence) sums the 2048
// partials with all 256 threads and emits vq_loss - saves the vq_final launch.
__global__ __launch_bounds__(256) void vq_outputs(
    const float4* __restrict__ z4, const float4* __restrict__ emb4,
    const float* __restrict__ idx_f, float4* __restrict__ out4,
    double* __restrict__ partials, int* __restrict__ done_count,
    float* __restrict__ out_loss) {
  const int tid = threadIdx.x;
  const int g0 = blockIdx.x * 256 + tid;
  double sum = 0.0;
#pragma unroll
  for (int it = 0; it < 4; ++it) {
    int e = g0 + it * (OUT_BLOCKS * 256);
    int row = e >> 4;
    int d4 = e & 15;
    int k = (int)idx_f[row];
    float4 zv = z4[e];
    float4 qv = emb4[k * 16 + d4];
    float dx = qv.x - zv.x, dy = qv.y - zv.y;
    float dz = qv.z - zv.z, dw = qv.w - zv.w;
    float4 o;
    o.x = zv.x + dx; o.y = zv.y + dy; o.z = zv.z + dz; o.w = zv.w + dw;
    out4[e] = o;
    sum += (double)dx * dx + (double)dy * dy + (double)dz * dz + (double)dw * dw;
  }
  for (int off = 32; off > 0; off >>= 1) sum += __shfl_down(sum, off, 64);
  __shared__ double wsum[4];
  __shared__ int is_last;
  if ((tid & 63) == 0) wsum[tid >> 6] = sum;
  __syncthreads();
  if (tid == 0) {
    partials[blockIdx.x] = wsum[0] + wsum[1] + wsum[2] + wsum[3];
    __threadfence();  // make partial visible device-wide before counting done
    int prev = atomicAdd(done_count, 1);
    is_last = (prev == OUT_BLOCKS - 1) ? 1 : 0;
  }
  __syncthreads();
  if (is_last) {
    double s = 0.0;
    for (int i = tid; i < OUT_BLOCKS; i += 256) s += partials[i];
    for (int off = 32; off > 0; off >>= 1) s += __shfl_down(s, off, 64);
    __shared__ double fsum[4];
    if ((tid & 63) == 0) fsum[tid >> 6] = s;
    __syncthreads();
    if (tid == 0)
      *out_loss = (float)(1.5 * (fsum[0] + fsum[1] + fsum[2] + fsum[3]) /
                          (double)((size_t)NROWS * DIM));
  }
}

extern "C" void kernel_launch(void* const* d_in, const int* in_sizes, int n_in,
                              void* d_out, int out_size, void* d_ws, size_t ws_size,
                              hipStream_t stream) {
  const float* z = (const float*)d_in[0];
  const float* emb = (const float*)d_in[1];
  float* out = (float*)d_out;
  float* out_q = out;                      // 8388608 floats
  float* out_loss = out + 8388608;         // 1 float
  float* idx_f = out + 8388609;            // 131072 floats

  char* ws = (char*)d_ws;
  double* partials = (double*)ws;                        // [0, 16384)
  double* enorm64 = (double*)(ws + 16384);               // [16384, 24576)
  int* flag_count = (int*)(ws + 24576);                  // 4 B
  int* done_count = (int*)(ws + 24580);                  // 4 B (+8 pad)
  unsigned short* ehl = (unsigned short*)(ws + 24592);   // 256 KB swizzled planes
  int* flag_rows = (int*)(ws + 24592 + 262144);          // 64 KB

  vq_prep<<<KCODES, 64, 0, stream>>>(emb, enorm64, ehl, flag_count, done_count);
  vq_passB<<<NROWS / 128, 256, 0, stream>>>(z, ehl, idx_f, flag_count, flag_rows);
  vq_refine<<<REFINE_BLOCKS, 256, 0, stream>>>(z, emb, enorm64, flag_count, flag_rows, idx_f);
  vq_outputs<<<OUT_BLOCKS, 256, 0, stream>>>((const float4*)z, (const float4*)emb,
                                             idx_f, (float4*)out_q, partials,
                                             done_count, out_loss);
}

// Round 16
// 89.888 us; speedup vs baseline: 1.7661x; 1.7661x over previous
//
#include <hip/hip_runtime.h>

#define NROWS 131072
#define DIM 64
#define KCODES 1024
#define MARGIN_DOT 2.5e-4f
#define WIN_FILTER 5e-4f
#define FLAG_CAP 16384
#define OUT_BLOCKS 2048
#define REFINE_BLOCKS 2048

typedef short bf16x8 __attribute__((ext_vector_type(8)));
typedef float f32x4 __attribute__((ext_vector_type(4)));

__device__ __forceinline__ unsigned short f32_to_bf16_rne(float f) {
  unsigned u = __float_as_uint(f);
  u += 0x7FFFu + ((u >> 16) & 1u);
  return (unsigned short)(u >> 16);
}

// async global->LDS, 16B per lane; lds dest = wave-uniform base + lane*16
__device__ __forceinline__ void gload_lds16(const void* g, void* l) {
  __builtin_amdgcn_global_load_lds(
      (const __attribute__((address_space(1))) unsigned int*)g,
      (__attribute__((address_space(3))) unsigned int*)l, 16, 0, 0);
}

// load 8 f32, split into bf16 hi/lo planes (RNE both)
__device__ __forceinline__ void cvt_split8(const float* p, bf16x8* hi, bf16x8* lo) {
  float4 f0 = *(const float4*)p;
  float4 f1 = *(const float4*)(p + 4);
  float fv[8] = {f0.x, f0.y, f0.z, f0.w, f1.x, f1.y, f1.z, f1.w};
  union { bf16x8 v; unsigned short u[8]; } H, L;
#pragma unroll
  for (int i = 0; i < 8; i++) {
    unsigned short h = f32_to_bf16_rne(fv[i]);
    float hf = __uint_as_float((unsigned)h << 16);
    H.u[i] = h;
    L.u[i] = f32_to_bf16_rne(fv[i] - hf);
  }
  *hi = H.v;
  *lo = L.v;
}

// ---------------- prep: flag init + enorm64 + swizzled split-bf16 emb tiles ----------------
__global__ __launch_bounds__(64) void vq_prep(const float* __restrict__ emb,
                                              double* __restrict__ enorm64,
                                              unsigned short* __restrict__ ehl,
                                              int* __restrict__ flag_count) {
  int k = blockIdx.x;
  int d = threadIdx.x;
  if (k == 0 && d == 0) *flag_count = 0;
  float v = emb[k * 64 + d];
  unsigned short h = f32_to_bf16_rne(v);
  float hf = __uint_as_float((unsigned)h << 16);
  unsigned short l = f32_to_bf16_rne(v - hf);
  int tile = k >> 4, cin = k & 15;
  int sidx = (cin * 64 + d) ^ ((cin & 7) << 3);
  ehl[tile * 2048 + sidx] = h;
  ehl[tile * 2048 + 1024 + sidx] = l;
  double s = (double)v * (double)v;
  for (int off = 32; off > 0; off >>= 1) s += __shfl_down(s, off, 64);
  if (d == 0) enorm64[k] = s;
}

// ---------------- pass B (R13-proven): MFMA argmax-dot, exact unpacked top-2 ----------------
// 1024 blocks x 4 waves; wave owns 32 rows x all codes; 4-slot ring, vmcnt(2).
// NOTE (R8-R15 evidence): ~61us is invariant across per-iter ring / bulk-stage /
// barrier-free reg-pipeline / rows-per-wave 16-64 / occupancy 17-52% -> this is
// the plain-HIP structure-class ceiling (~845 TF-equiv of the ~900 documented).
__global__ __launch_bounds__(256, 4) void vq_passB(
    const float* __restrict__ z, const unsigned short* __restrict__ ehl,
    float* __restrict__ idx_f, int* __restrict__ flag_count,
    int* __restrict__ flag_rows) {
  __shared__ unsigned short lds[4][2048];  // 4 x 4KB tile slots
  const int lane = threadIdx.x & 63;
  const int wv = threadIdx.x >> 6;
  const int lo4 = lane & 15;
  const int hi4 = lane >> 4;
  const int rowb = blockIdx.x * 128 + wv * 32;

  // prologue: stage tiles 0,1 (wave wv copies its 1KB quarter of each)
  gload_lds16(ehl + wv * 512 + lane * 8, &lds[0][wv * 512]);
  gload_lds16(ehl + 2048 + wv * 512 + lane * 8, &lds[1][wv * 512]);

  // z fragments: rt0 row = rowb + lo4, rt1 row = rowb + 16 + lo4
  bf16x8 zh0a, zh1a, zl0a, zl1a, zh0b, zh1b, zl0b, zl1b;
  {
    const float* zr0 = z + (size_t)(rowb + lo4) * 64 + hi4 * 8;
    const float* zr1 = z + (size_t)(rowb + 16 + lo4) * 64 + hi4 * 8;
    cvt_split8(zr0, &zh0a, &zl0a);
    cvt_split8(zr0 + 32, &zh1a, &zl1a);
    cvt_split8(zr1, &zh0b, &zl0b);
    cvt_split8(zr1 + 32, &zh1b, &zl1b);
  }

  float m1a = -3.4e38f, m2a = -3.4e38f, m1b = -3.4e38f, m2b = -3.4e38f;
  int i1a = 0, i1b = 0;
  const int swz = (lo4 & 7) << 3;
  const int i0 = (lo4 * 64 + hi4 * 8) ^ swz;
  const int i1 = (lo4 * 64 + 32 + hi4 * 8) ^ swz;

  for (int ct = 0; ct < 64; ct++) {
    int tn = (ct + 2 < 64) ? ct + 2 : 63;
    gload_lds16(ehl + tn * 2048 + wv * 512 + lane * 8, &lds[(ct + 2) & 3][wv * 512]);
    asm volatile("s_waitcnt vmcnt(2)" ::: "memory");  // own tile done; 2 in flight
    __builtin_amdgcn_s_barrier();
    asm volatile("" ::: "memory");

    const unsigned short* buf = lds[ct & 3];
    bf16x8 ah0 = *(const bf16x8*)(buf + i0);
    bf16x8 ah1 = *(const bf16x8*)(buf + i1);
    bf16x8 al0 = *(const bf16x8*)(buf + 1024 + i0);
    bf16x8 al1 = *(const bf16x8*)(buf + 1024 + i1);
    const int cbase = ct * 16 + hi4 * 4;

    f32x4 accA = {0.f, 0.f, 0.f, 0.f};
    f32x4 accB = {0.f, 0.f, 0.f, 0.f};
    __builtin_amdgcn_s_setprio(1);
    accA = __builtin_amdgcn_mfma_f32_16x16x32_bf16(ah0, zh0a, accA, 0, 0, 0);
    accB = __builtin_amdgcn_mfma_f32_16x16x32_bf16(ah0, zh0b, accB, 0, 0, 0);
    accA = __builtin_amdgcn_mfma_f32_16x16x32_bf16(ah1, zh1a, accA, 0, 0, 0);
    accB = __builtin_amdgcn_mfma_f32_16x16x32_bf16(ah1, zh1b, accB, 0, 0, 0);
    accA = __builtin_amdgcn_mfma_f32_16x16x32_bf16(al0, zh0a, accA, 0, 0, 0);
    accB = __builtin_amdgcn_mfma_f32_16x16x32_bf16(al0, zh0b, accB, 0, 0, 0);
    accA = __builtin_amdgcn_mfma_f32_16x16x32_bf16(al1, zh1a, accA, 0, 0, 0);
    accB = __builtin_amdgcn_mfma_f32_16x16x32_bf16(al1, zh1b, accB, 0, 0, 0);
    accA = __builtin_amdgcn_mfma_f32_16x16x32_bf16(ah0, zl0a, accA, 0, 0, 0);
    accB = __builtin_amdgcn_mfma_f32_16x16x32_bf16(ah0, zl0b, accB, 0, 0, 0);
    accA = __builtin_amdgcn_mfma_f32_16x16x32_bf16(ah1, zl1a, accA, 0, 0, 0);
    accB = __builtin_amdgcn_mfma_f32_16x16x32_bf16(ah1, zl1b, accB, 0, 0, 0);
    __builtin_amdgcn_s_setprio(0);

    // exact unpacked top-2 + argmax (strict > keeps lowest code per lane)
#pragma unroll
    for (int r = 0; r < 4; r++) {
      int code = cbase + r;
      {
        float s = accA[r];
        float pm = fminf(m1a, s);
        m2a = fmaxf(m2a, pm);
        if (s > m1a) i1a = code;
        m1a = fmaxf(m1a, s);
      }
      {
        float s = accB[r];
        float pm = fminf(m1b, s);
        m2b = fmaxf(m2b, pm);
        if (s > m1b) i1b = code;
        m1b = fmaxf(m1b, s);
      }
    }
  }

  // per-row merge over the 4 lane-groups (xor 16, 32) + emit
#pragma unroll
  for (int rt = 0; rt < 2; rt++) {
    float a1 = rt ? m1b : m1a;
    float a2 = rt ? m2b : m2a;
    int ai = rt ? i1b : i1a;
#pragma unroll
    for (int off = 16; off <= 32; off <<= 1) {
      float b1 = __shfl_xor(a1, off, 64);
      float b2 = __shfl_xor(a2, off, 64);
      int bi = __shfl_xor(ai, off, 64);
      float pm = fminf(a1, b1);
      a2 = fmaxf(fmaxf(a2, b2), pm);
      bool take = (b1 > a1) || (b1 == a1 && bi < ai);
      a1 = fmaxf(a1, b1);
      ai = take ? bi : ai;
    }
    if (lane < 16) {
      int row = rowb + rt * 16 + lane;
      idx_f[row] = (float)ai;
      if (a1 - a2 < MARGIN_DOT) {
        int pos = atomicAdd(flag_count, 1);
        if (pos < FLAG_CAP) flag_rows[pos] = row;
      }
    }
  }
}

// ---------------- refine: R5-proven per-row f32 filter + f64 candidate eval ----------------
__global__ __launch_bounds__(256) void vq_refine(const float* __restrict__ z,
                                                 const float* __restrict__ emb,
                                                 const double* __restrict__ enorm64,
                                                 const int* __restrict__ flag_count,
                                                 const int* __restrict__ flag_rows,
                                                 float* __restrict__ idx_f) {
  __shared__ float zs[64];
  __shared__ float smin[256];
  __shared__ int cand[256];
  __shared__ int ccount;
  __shared__ float A32s;
  int cnt = *flag_count;
  if (cnt > FLAG_CAP) cnt = FLAG_CAP;
  const int t = threadIdx.x;
  for (int i = blockIdx.x; i < cnt; i += gridDim.x) {
    int row = flag_rows[i];
    if (t < 64) zs[t] = z[(size_t)row * 64 + t];
    if (t == 0) ccount = 0;
    __syncthreads();
    if (t == 0) {  // sequential f64 row norm -> f32 (proven path)
      double a = 0.0;
      for (int d = 0; d < 64; d++) { double v = (double)zs[d]; a = fma(v, v, a); }
      A32s = (float)a;
    }
    float s_loc[4];
    float my = 3.4e38f;
#pragma unroll
    for (int q = 0; q < 4; q++) {
      int k = t * 4 + q;
      const float4* er = (const float4*)(emb + (size_t)k * 64);
      float dotf = 0.f;
#pragma unroll
      for (int d4 = 0; d4 < 16; d4++) {
        float4 e4 = er[d4];
        float4 zv = ((const float4*)zs)[d4];
        dotf = fmaf(e4.x, zv.x, dotf);
        dotf = fmaf(e4.y, zv.y, dotf);
        dotf = fmaf(e4.z, zv.z, dotf);
        dotf = fmaf(e4.w, zv.w, dotf);
      }
      s_loc[q] = -dotf;
      my = fminf(my, -dotf);
    }
    smin[t] = my;
    __syncthreads();
    for (int s = 128; s > 0; s >>= 1) {
      if (t < s) smin[t] = fminf(smin[t], smin[t + s]);
      __syncthreads();
    }
    float m1 = smin[0];
#pragma unroll
    for (int q = 0; q < 4; q++) {
      if (s_loc[q] - m1 < WIN_FILTER) {
        int p = atomicAdd(&ccount, 1);
        if (p < 256) cand[p] = t * 4 + q;
      }
    }
    __syncthreads();
    int cc = ccount;
    if (cc > 256) cc = 256;
    if (t < 64) {
      float bm = 3.4e38f;
      int bi = 0x7FFFFFFF;
      for (int c = 0; c < cc; c++) {
        int k = cand[c];
        double p = (double)emb[(size_t)k * 64 + t] * (double)zs[t];
        for (int off = 32; off > 0; off >>= 1) p += __shfl_down(p, off, 64);
        if (t == 0) {
          float C = (float)(2.0 * p);
          float B = (float)enorm64[k];
          float T = A32s + B;
          float dist = T - C;
          if (dist < bm || (dist == bm && k < bi)) { bm = dist; bi = k; }
        }
      }
      if (t == 0) idx_f[row] = (float)bi;
    }
    __syncthreads();
  }
}

// ---------------- outputs: quantized_ste + per-block loss partials ----------------
// (No device-scope fence here - R15 showed per-block __threadfence costs L2
// writebacks on multi-XCD CDNA, 6x write-BW collapse. Separate final kernel.)
__global__ __launch_bounds__(256) void vq_outputs(
    const float4* __restrict__ z4, const float4* __restrict__ emb4,
    const float* __restrict__ idx_f, float4* __restrict__ out4,
    double* __restrict__ partials) {
  const int tid = threadIdx.x;
  const int g0 = blockIdx.x * 256 + tid;
  double sum = 0.0;
#pragma unroll
  for (int it = 0; it < 4; ++it) {
    int e = g0 + it * (OUT_BLOCKS * 256);
    int row = e >> 4;
    int d4 = e & 15;
    int k = (int)idx_f[row];
    float4 zv = z4[e];
    float4 qv = emb4[k * 16 + d4];
    float dx = qv.x - zv.x, dy = qv.y - zv.y;
    float dz = qv.z - zv.z, dw = qv.w - zv.w;
    float4 o;
    o.x = zv.x + dx; o.y = zv.y + dy; o.z = zv.z + dz; o.w = zv.w + dw;
    out4[e] = o;
    sum += (double)dx * dx + (double)dy * dy + (double)dz * dz + (double)dw * dw;
  }
  for (int off = 32; off > 0; off >>= 1) sum += __shfl_down(sum, off, 64);
  __shared__ double wsum[4];
  if ((tid & 63) == 0) wsum[tid >> 6] = sum;
  __syncthreads();
  if (tid == 0) partials[blockIdx.x] = wsum[0] + wsum[1] + wsum[2] + wsum[3];
}

__global__ __launch_bounds__(256) void vq_final(const double* __restrict__ partials,
                                                float* __restrict__ out_loss) {
  int t = threadIdx.x;
  double s = 0.0;
  for (int i = t; i < OUT_BLOCKS; i += 256) s += partials[i];
  for (int off = 32; off > 0; off >>= 1) s += __shfl_down(s, off, 64);
  __shared__ double wsum[4];
  if ((t & 63) == 0) wsum[t >> 6] = s;
  __syncthreads();
  if (t == 0)
    *out_loss = (float)(1.5 * (wsum[0] + wsum[1] + wsum[2] + wsum[3]) /
                        (double)((size_t)NROWS * DIM));
}

extern "C" void kernel_launch(void* const* d_in, const int* in_sizes, int n_in,
                              void* d_out, int out_size, void* d_ws, size_t ws_size,
                              hipStream_t stream) {
  const float* z = (const float*)d_in[0];
  const float* emb = (const float*)d_in[1];
  float* out = (float*)d_out;
  float* out_q = out;                      // 8388608 floats
  float* out_loss = out + 8388608;         // 1 float
  float* idx_f = out + 8388609;            // 131072 floats

  char* ws = (char*)d_ws;
  double* partials = (double*)ws;                        // [0, 16384)
  double* enorm64 = (double*)(ws + 16384);               // [16384, 24576)
  int* flag_count = (int*)(ws + 24576);                  // 16 B
  unsigned short* ehl = (unsigned short*)(ws + 24592);   // 256 KB swizzled planes
  int* flag_rows = (int*)(ws + 24592 + 262144);          // 64 KB

  vq_prep<<<KCODES, 64, 0, stream>>>(emb, enorm64, ehl, flag_count);
  vq_passB<<<NROWS / 128, 256, 0, stream>>>(z, ehl, idx_f, flag_count, flag_rows);
  vq_refine<<<REFINE_BLOCKS, 256, 0, stream>>>(z, emb, enorm64, flag_count, flag_rows, idx_f);
  vq_outputs<<<OUT_BLOCKS, 256, 0, stream>>>((const float4*)z, (const float4*)emb,
                                             idx_f, (float4*)out_q, partials);
  vq_final<<<1, 256, 0, stream>>>(partials, out_loss);
}